// Round 3
// baseline (195.437 us; speedup 1.0000x reference)
//
#include <hip/hip_runtime.h>
#include <hip/hip_bf16.h>

// B=8, L=512, D=1024, H=16, HD=64
#define BB 8
#define LL 512
#define DD 1024
#define HH 16
#define HD 64

typedef __attribute__((ext_vector_type(8))) unsigned short u16x8;
typedef __attribute__((ext_vector_type(4))) unsigned short u16x4;
typedef __attribute__((ext_vector_type(8))) __bf16 bf16x8;
typedef __attribute__((ext_vector_type(4))) float f32x4;

#define DEV __device__ __forceinline__

DEV float bf2f(unsigned short u) { return __uint_as_float(((unsigned)u) << 16); }
DEV unsigned short f2bf(float f) {
    unsigned u = __float_as_uint(f);
    u += 0x7FFFu + ((u >> 16) & 1u);   // RNE; finite inputs
    return (unsigned short)(u >> 16);
}
DEV f32x4 mfma16(u16x8 a, u16x8 b, f32x4 c) {
    return __builtin_amdgcn_mfma_f32_16x16x32_bf16(
        __builtin_bit_cast(bf16x8, a), __builtin_bit_cast(bf16x8, b), c, 0, 0, 0);
}

// ------------------------------------------------- fp32 -> bf16 convert (x)
__global__ __launch_bounds__(256) void cvt_x(const float* __restrict__ in,
                                             unsigned short* __restrict__ out) {
    int i = blockIdx.x * 256 + threadIdx.x;   // 1M threads, 4 floats each
    f32x4 v = *(const f32x4*)(in + i * 4);
    u16x4 o;
    o[0] = f2bf(v[0]); o[1] = f2bf(v[1]); o[2] = f2bf(v[2]); o[3] = f2bf(v[3]);
    *(u16x4*)(out + i * 4) = o;
}

// ------------------------------------- transpose fp32 in -> bf16 out (RxC)
__global__ __launch_bounds__(256) void transpose_cvt(
    const float* __restrict__ in, unsigned short* __restrict__ out,
    int R, int C) {
    __shared__ unsigned short tile[32][33];
    int c0 = blockIdx.x * 32, r0 = blockIdx.y * 32;
    int tx = threadIdx.x & 31, ty = threadIdx.x >> 5;
#pragma unroll
    for (int i = 0; i < 32; i += 8)
        tile[ty + i][tx] = f2bf(in[(r0 + ty + i) * C + c0 + tx]);
    __syncthreads();
#pragma unroll
    for (int i = 0; i < 32; i += 8)
        out[(c0 + ty + i) * R + r0 + tx] = tile[tx][ty + i];
}

// ------------------------------------------------- pe table (512 x 64 fp32)
__global__ __launch_bounds__(256) void pe_fill(float* __restrict__ pe) {
    int idx = blockIdx.x * 256 + threadIdx.x;  // 32768
    int i = idx >> 6, d = idx & 63;
    int dd = d & 31;
    float inv = expf((float)dd * -0.2971077539347156f);  // -ln(10000)/31
    float ang = (float)(i - 256) * inv;
    pe[idx] = (d < 32) ? sinf(ang) : cosf(ang);
}

// --------------------------- pos GEMM: pe(512x64) @ w(64x2048) -> qp|kp bf16
__global__ __launch_bounds__(256) void posg(
    const float* __restrict__ pe, const float* __restrict__ w,
    unsigned short* __restrict__ qp, unsigned short* __restrict__ kp) {
    __shared__ float peS[64][64];
    __shared__ float wS[64][32];
    int c0 = blockIdx.x * 32, i0 = blockIdx.y * 64;
    int t = threadIdx.x;
#pragma unroll
    for (int j = 0; j < 16; ++j) {
        int o = t + j * 256;
        peS[o >> 6][o & 63] = pe[(i0 + (o >> 6)) * 64 + (o & 63)];
    }
#pragma unroll
    for (int j = 0; j < 8; ++j) {
        int o = t + j * 256;
        wS[o >> 5][o & 31] = w[(o >> 5) * 2048 + c0 + (o & 31)];
    }
    __syncthreads();
#pragma unroll
    for (int j = 0; j < 8; ++j) {
        int o = t + j * 256;
        int row = o >> 5, col = o & 31;
        float acc = 0.0f;
#pragma unroll
        for (int k = 0; k < 64; ++k) acc += peS[row][k] * wS[k][col];
        int c = c0 + col, i = i0 + row;
        unsigned short v = f2bf(acc);
        if (c < 1024) qp[i * 1024 + c] = v;
        else          kp[i * 1024 + (c - 1024)] = v;
    }
}

// ---------------------------------------------------------------- GEMM
// C = A(MxK bf16 rm) x Bt(NxK bf16 rm)^T
// MODE 0: scatter bf16 to q,k (B,H,L,HD), vt (B,H,HD,L)
// MODE 1: fout[row*N+col] = C + bias[col]  (fp32 out)
template <int MODE>
__global__ __launch_bounds__(256) void gemm_bt(
    const unsigned short* __restrict__ A, const unsigned short* __restrict__ Bt,
    int M, int N, int K, unsigned short* __restrict__ o0,
    unsigned short* __restrict__ o1, unsigned short* __restrict__ o2,
    float* __restrict__ fout, const float* __restrict__ bias) {
    __shared__ __align__(16) unsigned short As[128 * 32];
    __shared__ __align__(16) unsigned short Bs[128 * 32];
    int t = threadIdx.x;
    int m0 = blockIdx.y * 128, n0 = blockIdx.x * 128;
    int w = t >> 6, l = t & 63, lg = l >> 4, lc = l & 15;
    int wr = w >> 1, wc = w & 1;

    f32x4 acc[4][4] = {};

    int ar = t >> 2;
    int ak = (t & 3) * 8;
    const unsigned short* Ab = A + m0 * K;
    const unsigned short* Bb = Bt + n0 * K;

    for (int k0 = 0; k0 < K; k0 += 32) {
        u16x8 av0 = *(const u16x8*)(Ab + ar * K + k0 + ak);
        u16x8 av1 = *(const u16x8*)(Ab + (ar + 64) * K + k0 + ak);
        u16x8 bv0 = *(const u16x8*)(Bb + ar * K + k0 + ak);
        u16x8 bv1 = *(const u16x8*)(Bb + (ar + 64) * K + k0 + ak);
        __syncthreads();
        *(u16x8*)&As[ar * 32 + ak] = av0;
        *(u16x8*)&As[(ar + 64) * 32 + ak] = av1;
        *(u16x8*)&Bs[ar * 32 + ak] = bv0;
        *(u16x8*)&Bs[(ar + 64) * 32 + ak] = bv1;
        __syncthreads();
        u16x8 af[4], bf[4];
#pragma unroll
        for (int mm = 0; mm < 4; ++mm)
            af[mm] = *(const u16x8*)&As[(wr * 64 + mm * 16 + lc) * 32 + lg * 8];
#pragma unroll
        for (int nn = 0; nn < 4; ++nn)
            bf[nn] = *(const u16x8*)&Bs[(wc * 64 + nn * 16 + lc) * 32 + lg * 8];
#pragma unroll
        for (int mm = 0; mm < 4; ++mm)
#pragma unroll
            for (int nn = 0; nn < 4; ++nn)
                acc[mm][nn] = mfma16(af[mm], bf[nn], acc[mm][nn]);
    }

#pragma unroll
    for (int mm = 0; mm < 4; ++mm)
#pragma unroll
        for (int nn = 0; nn < 4; ++nn)
#pragma unroll
            for (int r = 0; r < 4; ++r) {
                int row = m0 + wr * 64 + mm * 16 + lg * 4 + r;
                int col = n0 + wc * 64 + nn * 16 + lc;
                float v = acc[mm][nn][r];
                if (MODE == 0) {
                    unsigned short bv = f2bf(v);
                    int bb = row >> 9, i = row & 511;
                    int which = col >> 10, dd = col & 1023;
                    int hh = dd >> 6, hd = dd & 63;
                    if (which == 0)
                        o0[((bb * HH + hh) * LL + i) * HD + hd] = bv;
                    else if (which == 1)
                        o1[((bb * HH + hh) * LL + i) * HD + hd] = bv;
                    else
                        o2[((bb * HH + hh) * HD + hd) * LL + i] = bv;
                } else {
                    fout[row * N + col] = v + bias[col];
                }
            }
}

// ---------------------------------------------------------------- attention
__global__ __launch_bounds__(256) void attn_k(
    const unsigned short* __restrict__ Q, const unsigned short* __restrict__ Kt,
    const unsigned short* __restrict__ Vt, const unsigned short* __restrict__ QP,
    const unsigned short* __restrict__ KP, const int* __restrict__ mask,
    const int* __restrict__ qmask, const float* __restrict__ shp,
    const float* __restrict__ bip, unsigned short* __restrict__ out) {
    __shared__ __align__(16) unsigned short P[32 * 512];  // 32KB, swizzled
    __shared__ float redM[4][32];
    __shared__ float redS[4][32];

    int bid = blockIdx.x;
    int it = bid & 15, h = (bid >> 4) & 15, b = bid >> 8;
    int i0 = it * 32;
    int t = threadIdx.x, w = t >> 6, l = t & 63, lg = l >> 4, lc = l & 15;
    int bh = b * HH + h;

    u16x8 aq[2][2], ap[2][2];
#pragma unroll
    for (int m = 0; m < 2; ++m)
#pragma unroll
        for (int ks = 0; ks < 2; ++ks) {
            int row = i0 + m * 16 + lc;
            aq[m][ks] = *(const u16x8*)(Q + (bh * LL + row) * HD + ks * 32 + lg * 8);
            ap[m][ks] = *(const u16x8*)(QP + row * DD + h * HD + ks * 32 + lg * 8);
        }

    f32x4 s[2][8] = {};
#pragma unroll
    for (int n = 0; n < 8; ++n) {
        int j = w * 128 + n * 16 + lc;
        const unsigned short* kb = Kt + (bh * LL + j) * HD + lg * 8;
        const unsigned short* pb = KP + j * DD + h * HD + lg * 8;
        u16x8 bk0 = *(const u16x8*)(kb);
        u16x8 bk1 = *(const u16x8*)(kb + 32);
        u16x8 bp0 = *(const u16x8*)(pb);
        u16x8 bp1 = *(const u16x8*)(pb + 32);
#pragma unroll
        for (int m = 0; m < 2; ++m) {
            s[m][n] = mfma16(aq[m][0], bk0, s[m][n]);
            s[m][n] = mfma16(aq[m][1], bk1, s[m][n]);
            s[m][n] = mfma16(ap[m][0], bp0, s[m][n]);
            s[m][n] = mfma16(ap[m][1], bp1, s[m][n]);
        }
    }

    float shift = *shp, gbias = *bip;
    int qmr[2][4];
#pragma unroll
    for (int m = 0; m < 2; ++m)
#pragma unroll
        for (int r = 0; r < 4; ++r)
            qmr[m][r] = qmask[b * LL + i0 + m * 16 + lg * 4 + r];
    int qmc[8], kmc[8];
#pragma unroll
    for (int n = 0; n < 8; ++n) {
        int j = w * 128 + n * 16 + lc;
        qmc[n] = qmask[b * LL + j];
        kmc[n] = mask[b * LL + j];
    }
    const float NEG = -2.0e9f;   // finite "-inf": real scores are > -2e6
#pragma unroll
    for (int m = 0; m < 2; ++m)
#pragma unroll
        for (int n = 0; n < 8; ++n)
#pragma unroll
            for (int r = 0; r < 4; ++r) {
                float v = s[m][n][r];
                int row = i0 + m * 16 + lg * 4 + r;
                int col = w * 128 + n * 16 + lc;
                v = (qmr[m][r] == qmc[n]) ? v : 0.0f;   // cross-speaker zero
                float dr = (float)(row - col);
                v -= shift * dr * dr + gbias;           // gaussian bias
                if (kmc[n] == 0) v = NEG;               // key padding
                s[m][n][r] = v;
            }

    float pm[2][4];
#pragma unroll
    for (int m = 0; m < 2; ++m)
#pragma unroll
        for (int r = 0; r < 4; ++r) {
            float v = s[m][0][r];
#pragma unroll
            for (int n = 1; n < 8; ++n) v = fmaxf(v, s[m][n][r]);
            v = fmaxf(v, __shfl_xor(v, 1));
            v = fmaxf(v, __shfl_xor(v, 2));
            v = fmaxf(v, __shfl_xor(v, 4));
            v = fmaxf(v, __shfl_xor(v, 8));
            pm[m][r] = v;
        }
    if (lc == 0) {
#pragma unroll
        for (int m = 0; m < 2; ++m)
#pragma unroll
            for (int r = 0; r < 4; ++r) redM[w][m * 16 + lg * 4 + r] = pm[m][r];
    }
    __syncthreads();
    float mrow[2][4], psum[2][4];
#pragma unroll
    for (int m = 0; m < 2; ++m)
#pragma unroll
        for (int r = 0; r < 4; ++r) {
            int rl = m * 16 + lg * 4 + r;
            mrow[m][r] = fmaxf(fmaxf(redM[0][rl], redM[1][rl]),
                               fmaxf(redM[2][rl], redM[3][rl]));
            psum[m][r] = 0.0f;
        }
#pragma unroll
    for (int m = 0; m < 2; ++m)
#pragma unroll
        for (int n = 0; n < 8; ++n)
#pragma unroll
            for (int r = 0; r < 4; ++r) {
                float p = expf(fminf(s[m][n][r] - mrow[m][r], 0.0f));
                s[m][n][r] = p;
                psum[m][r] += p;
            }
#pragma unroll
    for (int m = 0; m < 2; ++m)
#pragma unroll
        for (int r = 0; r < 4; ++r) {
            float v = psum[m][r];
            v += __shfl_xor(v, 1);
            v += __shfl_xor(v, 2);
            v += __shfl_xor(v, 4);
            v += __shfl_xor(v, 8);
            psum[m][r] = v;
        }
    if (lc == 0) {
#pragma unroll
        for (int m = 0; m < 2; ++m)
#pragma unroll
            for (int r = 0; r < 4; ++r) redS[w][m * 16 + lg * 4 + r] = psum[m][r];
    }
#pragma unroll
    for (int m = 0; m < 2; ++m)
#pragma unroll
        for (int n = 0; n < 8; ++n)
#pragma unroll
            for (int r = 0; r < 4; ++r) {
                int rl = m * 16 + lg * 4 + r;
                int j = w * 128 + n * 16 + lc;
                int off = (rl * 1024 + j * 2) ^ ((rl & 7) << 4);
                *(unsigned short*)((char*)P + off) = f2bf(s[m][n][r]);
            }
    __syncthreads();

    f32x4 o[2] = {};
    int d = w * 16 + lc;
#pragma unroll
    for (int ks = 0; ks < 16; ++ks) {
        u16x8 bv = *(const u16x8*)(Vt + (bh * HD + d) * LL + ks * 32 + lg * 8);
#pragma unroll
        for (int m = 0; m < 2; ++m) {
            int rl = m * 16 + lc;
            int off = (rl * 1024 + (ks * 32 + lg * 8) * 2) ^ ((rl & 7) << 4);
            u16x8 av = *(const u16x8*)((char*)P + off);
            o[m] = mfma16(av, bv, o[m]);
        }
    }
#pragma unroll
    for (int m = 0; m < 2; ++m)
#pragma unroll
        for (int r = 0; r < 4; ++r) {
            int rl = m * 16 + lg * 4 + r;
            float rs = redS[0][rl] + redS[1][rl] + redS[2][rl] + redS[3][rl];
            rs = fmaxf(rs, 1e-30f);
            int row = i0 + rl;
            out[(b * LL + row) * DD + h * HD + d] = f2bf(o[m][r] / rs);
        }
}

// ---------------------------------------------------------------- launch
extern "C" void kernel_launch(void* const* d_in, const int* in_sizes, int n_in,
                              void* d_out, int out_size, void* d_ws,
                              size_t ws_size, hipStream_t stream) {
    const float* x     = (const float*)d_in[0];
    const int*   mask  = (const int*)d_in[1];
    const int*   qmask = (const int*)d_in[2];
    const float* w_qkv = (const float*)d_in[3];
    const float* w_qkp = (const float*)d_in[4];
    const float* w_fc  = (const float*)d_in[5];
    const float* b_fc  = (const float*)d_in[6];
    const float* shift = (const float*)d_in[7];
    const float* bias  = (const float*)d_in[8];

    char* ws = (char*)d_ws;
    unsigned short* xb   = (unsigned short*)(ws);              //  8 MB (B*L, D) bf16
    unsigned short* qb   = (unsigned short*)(ws + 8388608);    //  8 MB (B,H,L,HD)
    unsigned short* kb   = (unsigned short*)(ws + 16777216);   //  8 MB (B,H,L,HD)
    unsigned short* vtb  = (unsigned short*)(ws + 25165824);   //  8 MB (B,H,HD,L)
    unsigned short* qp   = (unsigned short*)(ws + 33554432);   //  1 MB (L,D)
    unsigned short* kp   = (unsigned short*)(ws + 34603008);   //  1 MB (L,D)
    unsigned short* wqt  = (unsigned short*)(ws + 35651584);   //  6 MB (3D,D)
    unsigned short* wft  = (unsigned short*)(ws + 41943040);   //  2 MB (D,D)
    unsigned short* aout = (unsigned short*)(ws + 44040192);   //  8 MB (B,L,D)
    float*          pe   = (float*)(ws + 52428800);            // 128 KB (L,64)

    hipMemsetAsync(d_ws, 0, 52559872, stream);

    cvt_x<<<4096, 256, 0, stream>>>(x, xb);
    transpose_cvt<<<dim3(96, 32), 256, 0, stream>>>(w_qkv, wqt, 1024, 3072);
    transpose_cvt<<<dim3(32, 32), 256, 0, stream>>>(w_fc, wft, 1024, 1024);
    pe_fill<<<128, 256, 0, stream>>>(pe);
    posg<<<dim3(64, 8), 256, 0, stream>>>(pe, w_qkp, qp, kp);
    gemm_bt<0><<<dim3(24, 32), 256, 0, stream>>>(xb, wqt, 4096, 3072, 1024, qb,
                                                 kb, vtb, nullptr, nullptr);
    attn_k<<<2048, 256, 0, stream>>>(qb, kb, vtb, qp, kp, mask, qmask, shift,
                                     bias, aout);
    gemm_bt<1><<<dim3(8, 32), 256, 0, stream>>>(aout, wft, 4096, 1024, 1024,
                                                nullptr, nullptr, nullptr,
                                                (float*)d_out, b_fc);
}

// Round 4
// 167.707 us; speedup vs baseline: 1.1653x; 1.1653x over previous
//
#include <hip/hip_runtime.h>
#include <hip/hip_bf16.h>

// B=8, L=512, D=1024, H=16, HD=64
#define BB 8
#define LL 512
#define DD 1024
#define HH 16
#define HD 64
#define LOG2E 1.4426950408889634f

typedef __attribute__((ext_vector_type(8))) unsigned short u16x8;
typedef __attribute__((ext_vector_type(4))) unsigned short u16x4;
typedef __attribute__((ext_vector_type(8))) __bf16 bf16x8;
typedef __attribute__((ext_vector_type(4))) float f32x4;

#define DEV __device__ __forceinline__

DEV float bf2f(unsigned short u) { return __uint_as_float(((unsigned)u) << 16); }
DEV unsigned short f2bf(float f) {               // native v_cvt (RNE)
    return __builtin_bit_cast(unsigned short, (__bf16)f);
}
DEV f32x4 mfma16(u16x8 a, u16x8 b, f32x4 c) {
    return __builtin_amdgcn_mfma_f32_16x16x32_bf16(
        __builtin_bit_cast(bf16x8, a), __builtin_bit_cast(bf16x8, b), c, 0, 0, 0);
}
// async global->LDS, 16B per lane; LDS dest = wave-uniform base + lane*16
typedef __attribute__((address_space(1))) void gv_t;
typedef __attribute__((address_space(3))) void lv_t;
DEV void gload16(const void* g, void* l) {
    __builtin_amdgcn_global_load_lds((gv_t*)g, (lv_t*)l, 16, 0, 0);
}

// ------------------------------------------------- fp32 -> bf16 convert (x)
__global__ __launch_bounds__(256) void cvt_x(const float* __restrict__ in,
                                             unsigned short* __restrict__ out) {
    int i = blockIdx.x * 256 + threadIdx.x;   // 1M threads, 4 floats each
    f32x4 v = *(const f32x4*)(in + i * 4);
    u16x4 o;
    o[0] = f2bf(v[0]); o[1] = f2bf(v[1]); o[2] = f2bf(v[2]); o[3] = f2bf(v[3]);
    *(u16x4*)(out + i * 4) = o;
}

// ------------------------------------- transpose fp32 in -> bf16 out (RxC)
__global__ __launch_bounds__(256) void transpose_cvt(
    const float* __restrict__ in, unsigned short* __restrict__ out,
    int R, int C) {
    __shared__ unsigned short tile[32][33];
    int c0 = blockIdx.x * 32, r0 = blockIdx.y * 32;
    int tx = threadIdx.x & 31, ty = threadIdx.x >> 5;
#pragma unroll
    for (int i = 0; i < 32; i += 8)
        tile[ty + i][tx] = f2bf(in[(r0 + ty + i) * C + c0 + tx]);
    __syncthreads();
#pragma unroll
    for (int i = 0; i < 32; i += 8)
        out[(c0 + ty + i) * R + r0 + tx] = tile[tx][ty + i];
}

// ------------------------------------------------- pe table (512 x 64 fp32)
__global__ __launch_bounds__(256) void pe_fill(float* __restrict__ pe) {
    int idx = blockIdx.x * 256 + threadIdx.x;  // 32768
    int i = idx >> 6, d = idx & 63;
    int dd = d & 31;
    float inv = expf((float)dd * -0.2971077539347156f);  // -ln(10000)/31
    float ang = (float)(i - 256) * inv;
    pe[idx] = (d < 32) ? sinf(ang) : cosf(ang);
}

// --------------------------- pos GEMM: pe(512x64) @ w(64x2048) -> qp|kp bf16
// qp is pre-scaled by log2(e) (softmax via exp2)
__global__ __launch_bounds__(256) void posg(
    const float* __restrict__ pe, const float* __restrict__ w,
    unsigned short* __restrict__ qp, unsigned short* __restrict__ kp) {
    __shared__ float peS[64][64];
    __shared__ float wS[64][32];
    int c0 = blockIdx.x * 32, i0 = blockIdx.y * 64;
    int t = threadIdx.x;
#pragma unroll
    for (int j = 0; j < 16; ++j) {
        int o = t + j * 256;
        peS[o >> 6][o & 63] = pe[(i0 + (o >> 6)) * 64 + (o & 63)];
    }
#pragma unroll
    for (int j = 0; j < 8; ++j) {
        int o = t + j * 256;
        wS[o >> 5][o & 31] = w[(o >> 5) * 2048 + c0 + (o & 31)];
    }
    __syncthreads();
#pragma unroll
    for (int j = 0; j < 8; ++j) {
        int o = t + j * 256;
        int row = o >> 5, col = o & 31;
        float acc = 0.0f;
#pragma unroll
        for (int k = 0; k < 64; ++k) acc += peS[row][k] * wS[k][col];
        int c = c0 + col, i = i0 + row;
        if (c < 1024) qp[i * 1024 + c] = f2bf(acc * LOG2E);
        else          kp[i * 1024 + (c - 1024)] = f2bf(acc);
    }
}

// ---------------------------------------------------------------- GEMM
// C = A(MxK bf16 rm) x Bt(NxK bf16 rm)^T, global_load_lds staging, 1D grid
// with XCD swizzle. MODE 0: scatter bf16 to q(*log2e),k (B,H,L,HD), vt
// (B,H,HD,L). MODE 1: fout[row*N+col] = C + bias[col] (fp32)
template <int MODE>
__global__ __launch_bounds__(256) void gemm_bt(
    const unsigned short* __restrict__ A, const unsigned short* __restrict__ Bt,
    int M, int N, int K, int NBX, unsigned short* __restrict__ o0,
    unsigned short* __restrict__ o1, unsigned short* __restrict__ o2,
    float* __restrict__ fout, const float* __restrict__ bias) {
    __shared__ __align__(16) unsigned short As[128 * 32];
    __shared__ __align__(16) unsigned short Bs[128 * 32];
    int g = blockIdx.x;
    int swz = (g & 7) * (gridDim.x >> 3) + (g >> 3);   // XCD-contiguous chunks
    int bx = swz % NBX, by = swz / NBX;
    int m0 = by * 128, n0 = bx * 128;
    int t = threadIdx.x;
    int w = t >> 6, l = t & 63, lg = l >> 4, lc = l & 15;
    int wr = w >> 1, wc = w & 1;

    f32x4 acc[4][4] = {};

    int sr = w * 16 + (l >> 2);      // staging row 0..63
    int sk = (l & 3) * 8;
    const unsigned short* Ab = A + (m0 + sr) * K + sk;
    const unsigned short* Bb = Bt + (n0 + sr) * K + sk;
    unsigned short* dA0 = As + w * 512;           // rows w*16..w*16+15
    unsigned short* dA1 = As + 2048 + w * 512;    // rows 64+...
    unsigned short* dB0 = Bs + w * 512;
    unsigned short* dB1 = Bs + 2048 + w * 512;

    for (int k0 = 0; k0 < K; k0 += 32) {
        __syncthreads();                    // prev compute done; LDS reusable
        gload16(Ab + k0, dA0);
        gload16(Ab + 64 * K + k0, dA1);
        gload16(Bb + k0, dB0);
        gload16(Bb + 64 * K + k0, dB1);
        __syncthreads();                    // drains vmcnt -> tiles resident
        u16x8 af[4], bf[4];
#pragma unroll
        for (int mm = 0; mm < 4; ++mm)
            af[mm] = *(const u16x8*)&As[(wr * 64 + mm * 16 + lc) * 32 + lg * 8];
#pragma unroll
        for (int nn = 0; nn < 4; ++nn)
            bf[nn] = *(const u16x8*)&Bs[(wc * 64 + nn * 16 + lc) * 32 + lg * 8];
#pragma unroll
        for (int mm = 0; mm < 4; ++mm)
#pragma unroll
            for (int nn = 0; nn < 4; ++nn)
                acc[mm][nn] = mfma16(af[mm], bf[nn], acc[mm][nn]);
    }

#pragma unroll
    for (int mm = 0; mm < 4; ++mm)
#pragma unroll
        for (int nn = 0; nn < 4; ++nn)
#pragma unroll
            for (int r = 0; r < 4; ++r) {
                int row = m0 + wr * 64 + mm * 16 + lg * 4 + r;
                int col = n0 + wc * 64 + nn * 16 + lc;
                float v = acc[mm][nn][r];
                if (MODE == 0) {
                    int bb = row >> 9, i = row & 511;
                    int which = col >> 10, dd = col & 1023;
                    int hh = dd >> 6, hd = dd & 63;
                    if (which == 0)       // q: pre-scale for exp2 softmax
                        o0[((bb * HH + hh) * LL + i) * HD + hd] = f2bf(v * LOG2E);
                    else if (which == 1)
                        o1[((bb * HH + hh) * LL + i) * HD + hd] = f2bf(v);
                    else
                        o2[((bb * HH + hh) * HD + hd) * LL + i] = f2bf(v);
                } else {
                    fout[row * N + col] = v + bias[col];
                }
            }
}

// ---------------------------------------------------------------- attention
// scores arrive pre-scaled by log2e (via q/qp); gaussian bias term folded as
// shift*log2e; the uniform "-bias" term cancels in softmax and is dropped.
__global__ __launch_bounds__(256) void attn_k(
    const unsigned short* __restrict__ Q, const unsigned short* __restrict__ Kt,
    const unsigned short* __restrict__ Vt, const unsigned short* __restrict__ QP,
    const unsigned short* __restrict__ KP, const int* __restrict__ mask,
    const int* __restrict__ qmask, const float* __restrict__ shp,
    unsigned short* __restrict__ out) {
    __shared__ __align__(16) unsigned short P[32 * 512];  // 32KB, swizzled
    __shared__ float redM[4][32];
    __shared__ float redS[4][32];

    int g = blockIdx.x;
    int bid = ((g & 7) << 8) + (g >> 3);   // XCD swizzle: one b per XCD chunk
    int it = bid & 15, h = (bid >> 4) & 15, b = bid >> 8;
    int i0 = it * 32;
    int t = threadIdx.x, w = t >> 6, l = t & 63, lg = l >> 4, lc = l & 15;
    int bh = b * HH + h;

    u16x8 aq[2][2], ap[2][2];
#pragma unroll
    for (int m = 0; m < 2; ++m)
#pragma unroll
        for (int ks = 0; ks < 2; ++ks) {
            int row = i0 + m * 16 + lc;
            aq[m][ks] = *(const u16x8*)(Q + (bh * LL + row) * HD + ks * 32 + lg * 8);
            ap[m][ks] = *(const u16x8*)(QP + row * DD + h * HD + ks * 32 + lg * 8);
        }

    f32x4 s[2][8] = {};
#pragma unroll
    for (int n = 0; n < 8; ++n) {
        int j = w * 128 + n * 16 + lc;
        const unsigned short* kb = Kt + (bh * LL + j) * HD + lg * 8;
        const unsigned short* pb = KP + j * DD + h * HD + lg * 8;
        u16x8 bk0 = *(const u16x8*)(kb);
        u16x8 bk1 = *(const u16x8*)(kb + 32);
        u16x8 bp0 = *(const u16x8*)(pb);
        u16x8 bp1 = *(const u16x8*)(pb + 32);
#pragma unroll
        for (int m = 0; m < 2; ++m) {
            s[m][n] = mfma16(aq[m][0], bk0, s[m][n]);
            s[m][n] = mfma16(aq[m][1], bk1, s[m][n]);
            s[m][n] = mfma16(ap[m][0], bp0, s[m][n]);
            s[m][n] = mfma16(ap[m][1], bp1, s[m][n]);
        }
    }

    float shiftl = (*shp) * LOG2E;
    int qmr[2][4];
#pragma unroll
    for (int m = 0; m < 2; ++m)
#pragma unroll
        for (int r = 0; r < 4; ++r)
            qmr[m][r] = qmask[b * LL + i0 + m * 16 + lg * 4 + r];
    int qmc[8], kmc[8];
#pragma unroll
    for (int n = 0; n < 8; ++n) {
        int j = w * 128 + n * 16 + lc;
        qmc[n] = qmask[b * LL + j];
        kmc[n] = mask[b * LL + j];
    }
    const float NEG = -1.0e9f;   // real scores (log2-domain) stay > -3e6
#pragma unroll
    for (int m = 0; m < 2; ++m)
#pragma unroll
        for (int n = 0; n < 8; ++n)
#pragma unroll
            for (int r = 0; r < 4; ++r) {
                float v = s[m][n][r];
                int row = i0 + m * 16 + lg * 4 + r;
                int col = w * 128 + n * 16 + lc;
                v = (qmr[m][r] == qmc[n]) ? v : 0.0f;   // cross-speaker zero
                float dr = (float)(row - col);
                v = __builtin_fmaf(-shiftl * dr, dr, v); // gaussian (log2 dom)
                if (kmc[n] == 0) v = NEG;                // key padding
                s[m][n][r] = v;
            }

    float pm[2][4];
#pragma unroll
    for (int m = 0; m < 2; ++m)
#pragma unroll
        for (int r = 0; r < 4; ++r) {
            float v = s[m][0][r];
#pragma unroll
            for (int n = 1; n < 8; ++n) v = fmaxf(v, s[m][n][r]);
            v = fmaxf(v, __shfl_xor(v, 1));
            v = fmaxf(v, __shfl_xor(v, 2));
            v = fmaxf(v, __shfl_xor(v, 4));
            v = fmaxf(v, __shfl_xor(v, 8));
            pm[m][r] = v;
        }
    if (lc == 0) {
#pragma unroll
        for (int m = 0; m < 2; ++m)
#pragma unroll
            for (int r = 0; r < 4; ++r) redM[w][m * 16 + lg * 4 + r] = pm[m][r];
    }
    __syncthreads();
    float mrow[2][4], psum[2][4];
#pragma unroll
    for (int m = 0; m < 2; ++m)
#pragma unroll
        for (int r = 0; r < 4; ++r) {
            int rl = m * 16 + lg * 4 + r;
            mrow[m][r] = fmaxf(fmaxf(redM[0][rl], redM[1][rl]),
                               fmaxf(redM[2][rl], redM[3][rl]));
            psum[m][r] = 0.0f;
        }
#pragma unroll
    for (int m = 0; m < 2; ++m)
#pragma unroll
        for (int n = 0; n < 8; ++n)
#pragma unroll
            for (int r = 0; r < 4; ++r) {
                float p = __builtin_amdgcn_exp2f(s[m][n][r] - mrow[m][r]);
                s[m][n][r] = p;
                psum[m][r] += p;
            }
#pragma unroll
    for (int m = 0; m < 2; ++m)
#pragma unroll
        for (int r = 0; r < 4; ++r) {
            float v = psum[m][r];
            v += __shfl_xor(v, 1);
            v += __shfl_xor(v, 2);
            v += __shfl_xor(v, 4);
            v += __shfl_xor(v, 8);
            psum[m][r] = v;
        }
    if (lc == 0) {
#pragma unroll
        for (int m = 0; m < 2; ++m)
#pragma unroll
            for (int r = 0; r < 4; ++r) redS[w][m * 16 + lg * 4 + r] = psum[m][r];
    }
#pragma unroll
    for (int m = 0; m < 2; ++m)
#pragma unroll
        for (int n = 0; n < 8; ++n)
#pragma unroll
            for (int r = 0; r < 4; ++r) {
                int rl = m * 16 + lg * 4 + r;
                int j = w * 128 + n * 16 + lc;
                int off = (rl * 1024 + j * 2) ^ ((rl & 7) << 4);
                *(unsigned short*)((char*)P + off) = f2bf(s[m][n][r]);
            }
    __syncthreads();

    // PV: wave w owns cols d in [w*16,w*16+16); two indep. MFMA chains
    f32x4 oA[2] = {}, oB[2] = {};
    int d = w * 16 + lc;
#pragma unroll
    for (int ks = 0; ks < 8; ++ks) {
        u16x8 bv0 = *(const u16x8*)(Vt + (bh * HD + d) * LL + ks * 32 + lg * 8);
        u16x8 bv1 = *(const u16x8*)(Vt + (bh * HD + d) * LL + (ks + 8) * 32 + lg * 8);
#pragma unroll
        for (int m = 0; m < 2; ++m) {
            int rl = m * 16 + lc;
            int off0 = (rl * 1024 + (ks * 32 + lg * 8) * 2) ^ ((rl & 7) << 4);
            int off1 = (rl * 1024 + ((ks + 8) * 32 + lg * 8) * 2) ^ ((rl & 7) << 4);
            oA[m] = mfma16(*(const u16x8*)((char*)P + off0), bv0, oA[m]);
            oB[m] = mfma16(*(const u16x8*)((char*)P + off1), bv1, oB[m]);
        }
    }
#pragma unroll
    for (int m = 0; m < 2; ++m)
#pragma unroll
        for (int r = 0; r < 4; ++r) {
            int rl = m * 16 + lg * 4 + r;
            float rs = redS[0][rl] + redS[1][rl] + redS[2][rl] + redS[3][rl];
            float rinv = __builtin_amdgcn_rcpf(rs);   // rs >= 1
            int row = i0 + rl;
            out[(b * LL + row) * DD + h * HD + d] =
                f2bf((oA[m][r] + oB[m][r]) * rinv);
        }
}

// ---------------------------------------------------------------- launch
extern "C" void kernel_launch(void* const* d_in, const int* in_sizes, int n_in,
                              void* d_out, int out_size, void* d_ws,
                              size_t ws_size, hipStream_t stream) {
    const float* x     = (const float*)d_in[0];
    const int*   mask  = (const int*)d_in[1];
    const int*   qmask = (const int*)d_in[2];
    const float* w_qkv = (const float*)d_in[3];
    const float* w_qkp = (const float*)d_in[4];
    const float* w_fc  = (const float*)d_in[5];
    const float* b_fc  = (const float*)d_in[6];
    const float* shift = (const float*)d_in[7];
    // d_in[8] (bias) cancels in softmax — unused

    char* ws = (char*)d_ws;
    unsigned short* xb   = (unsigned short*)(ws);              //  8 MB
    unsigned short* qb   = (unsigned short*)(ws + 8388608);    //  8 MB (B,H,L,HD)
    unsigned short* kb   = (unsigned short*)(ws + 16777216);   //  8 MB (B,H,L,HD)
    unsigned short* vtb  = (unsigned short*)(ws + 25165824);   //  8 MB (B,H,HD,L)
    unsigned short* qp   = (unsigned short*)(ws + 33554432);   //  1 MB (L,D)
    unsigned short* kp   = (unsigned short*)(ws + 34603008);   //  1 MB (L,D)
    unsigned short* wqt  = (unsigned short*)(ws + 35651584);   //  6 MB (3D,D)
    unsigned short* wft  = (unsigned short*)(ws + 41943040);   //  2 MB (D,D)
    unsigned short* aout = (unsigned short*)(ws + 44040192);   //  8 MB (B,L,D)
    float*          pe   = (float*)(ws + 52428800);            // 128 KB

    cvt_x<<<4096, 256, 0, stream>>>(x, xb);
    transpose_cvt<<<dim3(96, 32), 256, 0, stream>>>(w_qkv, wqt, 1024, 3072);
    transpose_cvt<<<dim3(32, 32), 256, 0, stream>>>(w_fc, wft, 1024, 1024);
    pe_fill<<<128, 256, 0, stream>>>(pe);
    posg<<<dim3(64, 8), 256, 0, stream>>>(pe, w_qkp, qp, kp);
    gemm_bt<0><<<768, 256, 0, stream>>>(xb, wqt, 4096, 3072, 1024, 24, qb, kb,
                                        vtb, nullptr, nullptr);
    attn_k<<<2048, 256, 0, stream>>>(qb, kb, vtb, qp, kp, mask, qmask, shift,
                                     aout);
    gemm_bt<1><<<256, 256, 0, stream>>>(aout, wft, 4096, 1024, 1024, 8, nullptr,
                                        nullptr, nullptr, (float*)d_out, b_fc);
}